// Round 3
// baseline (730.388 us; speedup 1.0000x reference)
//
#include <hip/hip_runtime.h>
#include <math.h>

#define NJ 24
#define JD 3
#define TS 120
#define B_TOT 16384
#define ROWF 8640             // floats per batch row
#define ROWP 2160             // float4 per batch row
#define BROWS 16              // batch rows per block
#define NBLK (B_TOT / BROWS)  // 1024 blocks = 4/CU exactly
#define KTOT (BROWS * ROWP)   // 34560 float4 per block (contiguous)
#define CELLS (NJ * TS)       // 2880 output cells (n,t)
#define S1CH 16               // stage-1 reduction chunks
#define S1B (NBLK / S1CH)     // 64 block-partials per chunk

// Each block streams a CONTIGUOUS 16-row span (2 x 1.08 MB from src/tgt),
// accumulating squared diffs per (c,t) position into an LDS accumulator.
// Plane-split layout acc[j][p] (j = float4 component) makes the 4 ds_add_f32
// per thread stride-1 across lanes -> conflict-free. LDS atomics also make
// cross-wave position aliasing (p = k mod 2160 wraps) race-free w/o barriers.
__global__ __launch_bounds__(256, 4) void pj_accum(const float* __restrict__ src,
                                                   const float* __restrict__ tgt,
                                                   float* __restrict__ gpart) {
    __shared__ float acc[4 * ROWP];  // 34.56 KB -> 4 blocks/CU
    int tid = threadIdx.x;
    for (int i = tid; i < 4 * ROWP; i += 256) acc[i] = 0.0f;
    __syncthreads();

    const float4* s = (const float4*)src;
    const float4* t = (const float4*)tgt;
    long base = (long)blockIdx.x * KTOT;
    int p = tid;  // position within row (float4 units), maintained mod 2160
    #pragma unroll 5
    for (int k = tid; k < KTOT; k += 256) {   // 135 iters, no ragged lanes
        float4 a = s[base + k];
        float4 c = t[base + k];
        float dx = a.x - c.x, dy = a.y - c.y, dz = a.z - c.z, dw = a.w - c.w;
        atomicAdd(&acc[0 * ROWP + p], dx * dx);
        atomicAdd(&acc[1 * ROWP + p], dy * dy);
        atomicAdd(&acc[2 * ROWP + p], dz * dz);
        atomicAdd(&acc[3 * ROWP + p], dw * dw);
        p += 256;
        p = (p >= ROWP) ? p - ROWP : p;
    }
    __syncthreads();

    // Fold joint-dim: cell (n,t) = sum over d of plane[t&3][(3n+d)*30 + (t>>2)]
    float* gp = gpart + (long)blockIdx.x * CELLS;
    for (int cell = tid; cell < CELLS; cell += 256) {
        int n = cell / TS, tt = cell - n * TS;
        int b0 = (tt & 3) * ROWP + (tt >> 2);
        float ssum = acc[b0 + (3 * n + 0) * 30]
                   + acc[b0 + (3 * n + 1) * 30]
                   + acc[b0 + (3 * n + 2) * 30];
        gp[cell] = ssum;  // per-block partial, no atomics
    }
}

__global__ void pj_reduce1(const float* __restrict__ gpart, float* __restrict__ gpart2) {
    int cell = blockIdx.x * blockDim.x + threadIdx.x;  // grid.x = 12
    if (cell >= CELLS) return;
    const float* gp = gpart + (long)blockIdx.y * S1B * CELLS + cell;
    float sum = 0.f;
    #pragma unroll 4
    for (int b = 0; b < S1B; ++b) sum += gp[(long)b * CELLS];
    gpart2[blockIdx.y * CELLS + cell] = sum;
}

__global__ void pj_reduce2(const float* __restrict__ gpart2, float* __restrict__ out) {
    float local = 0.f;
    for (int cell = threadIdx.x; cell < CELLS; cell += 256) {
        float s = 0.f;
        #pragma unroll
        for (int g = 0; g < S1CH; ++g) s += gpart2[g * CELLS + cell];
        local += sqrtf(s);
    }
    for (int off = 32; off > 0; off >>= 1) local += __shfl_down(local, off, 64);
    __shared__ float red[4];
    int lane = threadIdx.x & 63, wid = threadIdx.x >> 6;
    if (lane == 0) red[wid] = local;
    __syncthreads();
    if (threadIdx.x == 0) out[0] = red[0] + red[1] + red[2] + red[3];
}

extern "C" void kernel_launch(void* const* d_in, const int* in_sizes, int n_in,
                              void* d_out, int out_size, void* d_ws, size_t ws_size,
                              hipStream_t stream) {
    const float* src = (const float*)d_in[0];
    const float* tgt = (const float*)d_in[1];
    float* gpart  = (float*)d_ws;               // 1024*2880*4 = 11.8 MB
    float* gpart2 = gpart + (long)NBLK * CELLS; // 16*2880*4 = 184 KB
    float* out = (float*)d_out;

    pj_accum<<<NBLK, 256, 0, stream>>>(src, tgt, gpart);
    pj_reduce1<<<dim3(12, S1CH), 256, 0, stream>>>(gpart, gpart2);
    pj_reduce2<<<1, 256, 0, stream>>>(gpart2, out);
}

// Round 5
// 201.760 us; speedup vs baseline: 3.6201x; 3.6201x over previous
//
#include <hip/hip_runtime.h>
#include <math.h>

// Problem constants
#define NJ   24
#define JD   3
#define TS   120
#define B_TOT 16384
#define CT   (NJ * JD * TS)   // 8640 (c,t) positions per batch row
#define CT4  (CT / 4)         // 2160 float4 positions
#define NCHUNK 512            // batch chunks
#define BPC  (B_TOT / NCHUNK) // 32 batches per chunk

typedef float vfloat4 __attribute__((ext_vector_type(4)));  // native vector: OK for nontemporal builtin

__global__ void pj_zero(float* __restrict__ sq) {
    int i = blockIdx.x * blockDim.x + threadIdx.x;
    if (i < CT) sq[i] = 0.0f;
}

__global__ void pj_accum(const float* __restrict__ src,
                         const float* __restrict__ tgt,
                         float* __restrict__ sq) {
    int p4 = blockIdx.x * blockDim.x + threadIdx.x;   // float4 position in [0, CT4)
    if (p4 >= CT4) return;
    const vfloat4* s = (const vfloat4*)src;
    const vfloat4* t = (const vfloat4*)tgt;
    long base = (long)blockIdx.y * BPC * CT4 + p4;
    float ax = 0.f, ay = 0.f, az = 0.f, aw = 0.f;
    #pragma unroll 8
    for (int b = 0; b < BPC; ++b) {
        vfloat4 a = __builtin_nontemporal_load(&s[base]);
        vfloat4 c = __builtin_nontemporal_load(&t[base]);
        vfloat4 d = a - c;
        ax += d.x * d.x; ay += d.y * d.y; az += d.z * d.z; aw += d.w * d.w;
        base += CT4;
    }
    atomicAdd(&sq[p4 * 4 + 0], ax);
    atomicAdd(&sq[p4 * 4 + 1], ay);
    atomicAdd(&sq[p4 * 4 + 2], az);
    atomicAdd(&sq[p4 * 4 + 3], aw);
}

__global__ void pj_finalize(const float* __restrict__ sq, float* __restrict__ out) {
    float local = 0.0f;
    // 2880 (n,t) cells; each sums 3 joint-dim rows then sqrt
    for (int i = threadIdx.x; i < NJ * TS; i += blockDim.x) {
        int n = i / TS, t = i - (i / TS) * TS;
        float s = sq[(3 * n + 0) * TS + t]
                + sq[(3 * n + 1) * TS + t]
                + sq[(3 * n + 2) * TS + t];
        local += sqrtf(s);
    }
    // wave reduce (64 lanes)
    for (int off = 32; off > 0; off >>= 1)
        local += __shfl_down(local, off, 64);
    __shared__ float red[4];
    int lane = threadIdx.x & 63, wid = threadIdx.x >> 6;
    if (lane == 0) red[wid] = local;
    __syncthreads();
    if (threadIdx.x == 0) {
        float tot = 0.f;
        int nw = blockDim.x >> 6;
        for (int w = 0; w < nw; ++w) tot += red[w];
        out[0] = tot;
    }
}

extern "C" void kernel_launch(void* const* d_in, const int* in_sizes, int n_in,
                              void* d_out, int out_size, void* d_ws, size_t ws_size,
                              hipStream_t stream) {
    const float* src = (const float*)d_in[0];
    const float* tgt = (const float*)d_in[1];
    float* sq = (float*)d_ws;          // 8640 floats = 34.6 KB scratch
    float* out = (float*)d_out;

    pj_zero<<<(CT + 255) / 256, 256, 0, stream>>>(sq);

    dim3 grid((CT4 + 255) / 256, NCHUNK);
    pj_accum<<<grid, 256, 0, stream>>>(src, tgt, sq);

    pj_finalize<<<1, 256, 0, stream>>>(sq, out);
}